// Round 2
// baseline (77.686 us; speedup 1.0000x reference)
//
#include <hip/hip_runtime.h>
#include <math.h>

#define S_    10
#define C_    48
#define HWD   64
#define M_    512
#define PADK  4
#define PAIRS 20           // S_ * N(=2)
#define PITCH2 10240       // PAIRS*M_  (transposed ws pitch, floats)
#define YPITCH 516         // LDS pitch for y chunk (mult of 4; 516%32=4 -> 2-way = free)

// ws layout (float offsets)
#define OFF_XH 0
#define OFF_YH (C_ * PITCH2)            // 491520
#define OFF_CM (2 * C_ * PITCH2)        // colmax: PAIRS*M_ floats

__device__ __forceinline__ int gidx(int n, int c, int h, int w, int d) {
  return (((n * C_ + c) * HWD + h) * HWD + w) * HWD + d;
}

// ---- kernel 1: fused  y-mean + center + L2-normalize + zero colmax -------
// grid = S_ blocks x 1024 threads; block s handles both n for sample s.
__global__ __launch_bounds__(1024, 4) void k_prep(
    const float* __restrict__ x, const float* __restrict__ y,
    const int* __restrict__ hi, const int* __restrict__ wi,
    const int* __restrict__ di, float* __restrict__ ws) {
  int s = blockIdx.x;
  int t = threadIdx.x;
  int h0 = hi[s] - PADK, w0 = wi[s] - PADK, d0 = di[s] - PADK;
  __shared__ float mu[C_];

  // phase A: per-channel mean of y over 1024 (n,m), c-major mapping.
  // 768 active threads: c = t>>4 (48 channels), g = t&15 (16 partials/c).
  if (t < 768) {
    int c = t >> 4, g = t & 15;
    float sum = 0.f;
#pragma unroll
    for (int j = 0; j < 64; ++j) {
      int i = g * 64 + j;              // 0..1023 over (n,m)
      int n = i >> 9, m = i & 511;
      sum += y[gidx(n, c, h0 + (m >> 6), w0 + ((m >> 3) & 7), d0 + (m & 7))];
    }
    // reduce across the 16-lane group (aligned, offsets < 16 stay in-group)
    sum += __shfl_xor(sum, 1);
    sum += __shfl_xor(sum, 2);
    sum += __shfl_xor(sum, 4);
    sum += __shfl_xor(sum, 8);
    if (g == 0) mu[c] = sum * (1.0f / 1024.0f);
  }
  // zero this sample's colmax slots (2 pairs * 512 = 1024 floats)
  ws[OFF_CM + s * 1024 + t] = 0.f;
  __syncthreads();

  // phase B: thread = (n, m) column; center by y-mean, normalize, store [c][col].
  int n = t >> 9, m = t & 511;
  int pair = s * 2 + n;
  int base = gidx(n, 0, h0 + (m >> 6), w0 + ((m >> 3) & 7), d0 + (m & 7));
  float v[C_];
  float ss;

  // y column
  ss = 0.f;
#pragma unroll
  for (int c = 0; c < C_; ++c) {
    v[c] = y[base + c * (HWD * HWD * HWD)] - mu[c];
    ss += v[c] * v[c];
  }
  {
    float sc = 1.0f / fmaxf(sqrtf(ss), 1e-12f);
    float* outp = ws + OFF_YH + pair * M_ + m;
#pragma unroll
    for (int c = 0; c < C_; ++c) outp[c * PITCH2] = v[c] * sc;
  }
  // x column (reuses v[] registers)
  ss = 0.f;
#pragma unroll
  for (int c = 0; c < C_; ++c) {
    v[c] = x[base + c * (HWD * HWD * HWD)] - mu[c];
    ss += v[c] * v[c];
  }
  {
    float sc = 1.0f / fmaxf(sqrtf(ss), 1e-12f);
    float* outp = ws + OFF_XH + pair * M_ + m;
#pragma unroll
    for (int c = 0; c < C_; ++c) outp[c * PITCH2] = v[c] * sc;
  }
}

// ---- kernel 2: dist + row-softmax + column-max (atomic) ------------------
// grid = PAIRS*16 blocks x 256 thr; block = (pair, tile of 32 rows); 8 rows/wave.
__global__ __launch_bounds__(256, 4) void k_main(const float* __restrict__ xh,
                                                 const float* __restrict__ yh,
                                                 float* __restrict__ colmax) {
  int b = blockIdx.x;
  int pair = b >> 4, tile = b & 15;
  int t = threadIdx.x, lane = t & 63, wv = t >> 6;

  __shared__ float xl[C_ * 32];        // x tile: [c][row] (32 rows)
  __shared__ float yl[12 * YPITCH];    // y chunk: [c_rel][p]

  // stage x tile: 48 c-rows of 32 floats = 384 float4s
  const float* xsrc = xh + pair * M_ + tile * 32;
#pragma unroll
  for (int i = 0; i < 2; ++i) {
    int li = t + 256 * i;
    if (li < 384) {
      int c = li >> 3, r4 = (li & 7) << 2;
      *(float4*)(xl + c * 32 + r4) = *(const float4*)(xsrc + c * PITCH2 + r4);
    }
  }

  float acc[8][8];
#pragma unroll
  for (int r = 0; r < 8; ++r)
#pragma unroll
    for (int k = 0; k < 8; ++k) acc[r][k] = 0.f;

  const float* ysrc = yh + pair * M_;
  for (int chunk = 0; chunk < 4; ++chunk) {
    __syncthreads();                    // also covers xl on first iteration
#pragma unroll
    for (int i = 0; i < 6; ++i) {       // 12 channels x 512 = 1536 float4s
      int li = t + 256 * i;
      int cr = li >> 7, p4 = (li & 127) << 2;
      *(float4*)(yl + cr * YPITCH + p4) =
          *(const float4*)(ysrc + (chunk * 12 + cr) * PITCH2 + p4);
    }
    __syncthreads();
#pragma unroll
    for (int cr = 0; cr < 12; ++cr) {
      float yv[8];
#pragma unroll
      for (int k = 0; k < 8; ++k) yv[k] = yl[cr * YPITCH + lane + 64 * k];
      int c = chunk * 12 + cr;
#pragma unroll
      for (int r4 = 0; r4 < 2; ++r4) {
        float4 xv = *(const float4*)(xl + c * 32 + wv * 8 + r4 * 4); // wave-uniform: broadcast
#pragma unroll
        for (int k = 0; k < 8; ++k) {
          acc[r4 * 4 + 0][k] += xv.x * yv[k];
          acc[r4 * 4 + 1][k] += xv.y * yv[k];
          acc[r4 * 4 + 2][k] += xv.z * yv[k];
          acc[r4 * 4 + 3][k] += xv.w * yv[k];
        }
      }
    }
  }

  // epilogue: per row min -> softmax over p -> accumulate column max
  float cmax[8];
#pragma unroll
  for (int k = 0; k < 8; ++k) cmax[k] = 0.f;

#pragma unroll
  for (int r = 0; r < 8; ++r) {
    float dmin = 3.4e38f;
#pragma unroll
    for (int k = 0; k < 8; ++k) {
      float d = 1.0f - acc[r][k];
      acc[r][k] = d;
      dmin = fminf(dmin, d);
    }
#pragma unroll
    for (int off = 32; off; off >>= 1) dmin = fminf(dmin, __shfl_xor(dmin, off));
    float inv = 2.0f / (dmin + 1e-5f);  // logits = 2 - d*inv <= 2, no overflow
    float e[8], sm = 0.f;
#pragma unroll
    for (int k = 0; k < 8; ++k) {
      e[k] = __expf(2.0f - acc[r][k] * inv);
      sm += e[k];
    }
#pragma unroll
    for (int off = 32; off; off >>= 1) sm += __shfl_xor(sm, off);
    float rs = 1.0f / sm;
#pragma unroll
    for (int k = 0; k < 8; ++k) cmax[k] = fmaxf(cmax[k], e[k] * rs);
  }
  // positive floats: uint compare == float compare; atomicMax is order-independent
#pragma unroll
  for (int k = 0; k < 8; ++k)
    atomicMax((unsigned int*)&colmax[pair * M_ + lane + 64 * k],
              __float_as_uint(cmax[k]));
}

// ---- kernel 3: mean over p, -log, average -> scalar ----------------------
// 1 block x 640 threads = 10 waves; wave w handles pairs 2w, 2w+1.
__global__ void k_final(const float* __restrict__ colmax, float* __restrict__ out) {
  int t = threadIdx.x, lane = t & 63, wv = t >> 6;
  __shared__ float part[10];
  float loc = 0.f;
#pragma unroll
  for (int q = 0; q < 2; ++q) {
    int pair = wv * 2 + q;
    float sum = 0.f;
#pragma unroll
    for (int k = 0; k < 8; ++k) sum += colmax[pair * M_ + lane + 64 * k];
#pragma unroll
    for (int off = 32; off; off >>= 1) sum += __shfl_xor(sum, off);
    loc += -logf(sum * (1.0f / 512.0f) + 1e-5f);
  }
  if (lane == 0) part[wv] = loc;
  __syncthreads();
  if (t == 0) {
    float tot = 0.f;
#pragma unroll
    for (int i = 0; i < 10; ++i) tot += part[i];
    out[0] = tot * (1.0f / (float)PAIRS);
  }
}

extern "C" void kernel_launch(void* const* d_in, const int* in_sizes, int n_in,
                              void* d_out, int out_size, void* d_ws, size_t ws_size,
                              hipStream_t stream) {
  const float* x = (const float*)d_in[0];
  const float* y = (const float*)d_in[1];
  const int* hi = (const int*)d_in[2];
  const int* wi = (const int*)d_in[3];
  const int* di = (const int*)d_in[4];
  float* ws = (float*)d_ws;
  float* out = (float*)d_out;

  k_prep<<<S_, 1024, 0, stream>>>(x, y, hi, wi, di, ws);
  k_main<<<PAIRS * 16, 256, 0, stream>>>(ws + OFF_XH, ws + OFF_YH, ws + OFF_CM);
  k_final<<<1, 640, 0, stream>>>(ws + OFF_CM, out);
}

// Round 3
// 53.226 us; speedup vs baseline: 1.4595x; 1.4595x over previous
//
#include <hip/hip_runtime.h>
#include <math.h>

#define S_    10
#define C_    48
#define HWD   64
#define M_    512
#define PADK  4
#define PAIRS 20           // S_ * N(=2)
#define PITCH2 10240       // PAIRS*M_  (transposed ws pitch, floats)
#define YPITCH 516         // LDS pitch (516%32=4 -> only 2-way bank alias = free)
#define CSTRIDE (HWD * HWD * HWD)   // 262144 floats between channel planes

// ws layout (float offsets)
#define OFF_XH  0
#define OFF_YH  (C_ * PITCH2)             // 491520
#define OFF_CM  (2 * C_ * PITCH2)         // colmax (uint-encoded floats), 10240
#define OFF_MU  (OFF_CM + PAIRS * M_)     // 993280, 480 floats
#define OFF_CNT (OFF_MU + 480)            // 20 uint pair-arrival counters
#define OFF_ALL (OFF_CNT + 20)            // 1 uint global pair-done counter
#define OFF_PL  (OFF_ALL + 1)             // 20 float pair losses

__device__ __forceinline__ int gidx(int n, int c, int h, int w, int d) {
  return (((n * C_ + c) * HWD + h) * HWD + w) * HWD + d;
}

// ---- kernel 1: per-(s,c) mean of y over N x M; also zero colmax+counters --
// 480 blocks x 64 threads (wide TLP for the scattered gather).
__global__ void k_mu(const float* __restrict__ y, const int* __restrict__ hi,
                     const int* __restrict__ wi, const int* __restrict__ di,
                     float* __restrict__ ws) {
  int b = blockIdx.x, t = threadIdx.x;
  if (b < 160) ws[OFF_CM + b * 64 + t] = 0.f;           // zero colmax (10240)
  if (b == 160 && t < 41) ws[OFF_CNT + t] = 0.f;        // zero counters + pl
  int s = b / C_, c = b % C_;
  int h0 = hi[s] - PADK, w0 = wi[s] - PADK, d0 = di[s] - PADK;
  float sum = 0.f;
#pragma unroll
  for (int j = 0; j < 16; ++j) {
    int i = t + 64 * j;          // 0..1023 over (n,m)
    int n = i >> 9, m = i & 511;
    sum += y[gidx(n, c, h0 + (m >> 6), w0 + ((m >> 3) & 7), d0 + (m & 7))];
  }
#pragma unroll
  for (int off = 32; off; off >>= 1) sum += __shfl_xor(sum, off);
  if (t == 0) ws[OFF_MU + b] = sum * (1.0f / 1024.0f);
}

// ---- kernel 2: gather, center, L2-normalize, store transposed [c][col] ----
// 320 blocks x 256 thr; 4 lanes per column (12 channels each).
__global__ void k_norm(const float* __restrict__ x, const float* __restrict__ y,
                       const int* __restrict__ hi, const int* __restrict__ wi,
                       const int* __restrict__ di, float* __restrict__ ws) {
  int g = blockIdx.x * 256 + threadIdx.x;   // 0..81919
  int col = g >> 2;                         // 0..20479
  int q = threadIdx.x & 3;                  // c-quarter: channels q*12..q*12+11
  int which = col >= 10240;                 // 0 = y, 1 = x
  int cix = which ? col - 10240 : col;
  int pair = cix >> 9, m = cix & 511;
  int s = pair >> 1, n = pair & 1;
  int h0 = hi[s] - PADK, w0 = wi[s] - PADK, d0 = di[s] - PADK;
  int base = gidx(n, 0, h0 + (m >> 6), w0 + ((m >> 3) & 7), d0 + (m & 7));
  const float* src = which ? x : y;
  const float* mus = ws + OFF_MU + s * C_;
  int c0 = q * 12;
  float v[12];
  float ss = 0.f;
#pragma unroll
  for (int j = 0; j < 12; ++j) {
    v[j] = src[base + (c0 + j) * CSTRIDE] - mus[c0 + j];
    ss += v[j] * v[j];
  }
  // combine the 4 quarters of this column (aligned 4-lane group)
  ss += __shfl_xor(ss, 1);
  ss += __shfl_xor(ss, 2);
  float sc = 1.0f / fmaxf(sqrtf(ss), 1e-12f);
  float* outp = ws + (which ? OFF_XH : OFF_YH) + pair * M_ + m;
#pragma unroll
  for (int j = 0; j < 12; ++j) outp[(c0 + j) * PITCH2] = v[j] * sc;
}

// ---- kernel 3: dist + row-softmax + column-max + fused final --------------
// 320 blocks x 256 thr; block = (pair, tile of 32 rows); 8 rows/wave.
__global__ __launch_bounds__(256, 4) void k_main(const float* __restrict__ xh,
                                                 const float* __restrict__ yh,
                                                 float* __restrict__ ws,
                                                 float* __restrict__ out) {
  int b = blockIdx.x;
  int pair = b >> 4, tile = b & 15;
  int t = threadIdx.x, lane = t & 63, wv = t >> 6;

  __shared__ float xl[C_ * 32];        // x tile: [c][row] (32 rows)
  __shared__ float yl[12 * YPITCH];    // y chunk: [c_rel][p]

  const float* xsrc = xh + pair * M_ + tile * 32;
#pragma unroll
  for (int i = 0; i < 2; ++i) {
    int li = t + 256 * i;              // 384 float4s
    if (li < 384) {
      int c = li >> 3, r4 = (li & 7) << 2;
      *(float4*)(xl + c * 32 + r4) = *(const float4*)(xsrc + c * PITCH2 + r4);
    }
  }

  float acc[8][8];
#pragma unroll
  for (int r = 0; r < 8; ++r)
#pragma unroll
    for (int k = 0; k < 8; ++k) acc[r][k] = 0.f;

  const float* ysrc = yh + pair * M_;
  for (int chunk = 0; chunk < 4; ++chunk) {
    __syncthreads();
#pragma unroll
    for (int i = 0; i < 6; ++i) {      // 12 channels x 512 = 1536 float4s
      int li = t + 256 * i;
      int cr = li >> 7, p4 = (li & 127) << 2;
      *(float4*)(yl + cr * YPITCH + p4) =
          *(const float4*)(ysrc + (chunk * 12 + cr) * PITCH2 + p4);
    }
    __syncthreads();
#pragma unroll
    for (int cr = 0; cr < 12; ++cr) {
      float yv[8];
#pragma unroll
      for (int k = 0; k < 8; ++k) yv[k] = yl[cr * YPITCH + lane + 64 * k];
      int c = chunk * 12 + cr;
#pragma unroll
      for (int r4 = 0; r4 < 2; ++r4) {
        float4 xv = *(const float4*)(xl + c * 32 + wv * 8 + r4 * 4); // broadcast
#pragma unroll
        for (int k = 0; k < 8; ++k) {
          acc[r4 * 4 + 0][k] += xv.x * yv[k];
          acc[r4 * 4 + 1][k] += xv.y * yv[k];
          acc[r4 * 4 + 2][k] += xv.z * yv[k];
          acc[r4 * 4 + 3][k] += xv.w * yv[k];
        }
      }
    }
  }

  // epilogue: per row min -> softmax over p -> column-max accumulate
  float cmax[8];
#pragma unroll
  for (int k = 0; k < 8; ++k) cmax[k] = 0.f;
#pragma unroll
  for (int r = 0; r < 8; ++r) {
    float dmin = 3.4e38f;
#pragma unroll
    for (int k = 0; k < 8; ++k) {
      float d = 1.0f - acc[r][k];
      acc[r][k] = d;
      dmin = fminf(dmin, d);
    }
#pragma unroll
    for (int off = 32; off; off >>= 1) dmin = fminf(dmin, __shfl_xor(dmin, off));
    float inv = 2.0f / (dmin + 1e-5f);  // logits <= 2, no overflow
    float e[8], sm = 0.f;
#pragma unroll
    for (int k = 0; k < 8; ++k) {
      e[k] = __expf(2.0f - acc[r][k] * inv);
      sm += e[k];
    }
#pragma unroll
    for (int off = 32; off; off >>= 1) sm += __shfl_xor(sm, off);
    float rs = 1.0f / sm;
#pragma unroll
    for (int k = 0; k < 8; ++k) cmax[k] = fmaxf(cmax[k], e[k] * rs);
  }
  unsigned* cmu = (unsigned*)(ws + OFF_CM) + pair * M_;
#pragma unroll
  for (int k = 0; k < 8; ++k)
    atomicMax(&cmu[lane + 64 * k], __float_as_uint(cmax[k]));

  // ---- fused final: last block per pair reduces; last pair writes out ----
  __threadfence();
  __shared__ unsigned arr;
  if (t == 0) arr = atomicAdd((unsigned*)(ws + OFF_CNT) + pair, 1u);
  __syncthreads();
  if (arr == 15) {
    // atomic reads: coherent across XCDs
    float sum = __uint_as_float(atomicOr(&cmu[t], 0u)) +
                __uint_as_float(atomicOr(&cmu[t + 256], 0u));
#pragma unroll
    for (int off = 32; off; off >>= 1) sum += __shfl_xor(sum, off);
    __shared__ float red[4];
    if (lane == 0) red[wv] = sum;
    __syncthreads();
    if (t == 0) {
      float tot = red[0] + red[1] + red[2] + red[3];
      float loss = -logf(tot * (1.0f / 512.0f) + 1e-5f);
      atomicExch((unsigned*)(ws + OFF_PL) + pair, __float_as_uint(loss));
      __threadfence();
      unsigned d = atomicAdd((unsigned*)(ws + OFF_ALL), 1u);
      if (d == PAIRS - 1) {
        float tt = 0.f;
        for (int i = 0; i < PAIRS; ++i)
          tt += __uint_as_float(atomicOr((unsigned*)(ws + OFF_PL) + i, 0u));
        out[0] = tt * (1.0f / (float)PAIRS);
      }
    }
  }
}

extern "C" void kernel_launch(void* const* d_in, const int* in_sizes, int n_in,
                              void* d_out, int out_size, void* d_ws, size_t ws_size,
                              hipStream_t stream) {
  const float* x = (const float*)d_in[0];
  const float* y = (const float*)d_in[1];
  const int* hi = (const int*)d_in[2];
  const int* wi = (const int*)d_in[3];
  const int* di = (const int*)d_in[4];
  float* ws = (float*)d_ws;
  float* out = (float*)d_out;

  k_mu<<<S_ * C_, 64, 0, stream>>>(y, hi, wi, di, ws);
  k_norm<<<320, 256, 0, stream>>>(x, y, hi, wi, di, ws);
  k_main<<<PAIRS * 16, 256, 0, stream>>>(ws + OFF_XH, ws + OFF_YH, ws, out);
}

// Round 4
// 51.742 us; speedup vs baseline: 1.5014x; 1.0287x over previous
//
#include <hip/hip_runtime.h>
#include <math.h>

#define S_    10
#define C_    48
#define HWD   64
#define M_    512
#define PADK  4
#define PAIRS 20           // S_ * N(=2)
#define YPITCH 516         // LDS pitch (516%32=4 -> only 2-way bank alias = free)

// Compact gathered layout: G[(s*96 + 2*c + n)*512 + m]  (one 2KB run per (s,c,n))
// ws layout (float offsets)
#define OFF_GY  0
#define OFF_GX  491520                    // 10*48*2*512
#define OFF_CM  (2 * 491520)              // colmax (uint-encoded floats), 10240
#define OFF_MU  (OFF_CM + PAIRS * M_)     // 480 floats
#define OFF_CNT (OFF_MU + 480)            // 20 uint pair-arrival counters
#define OFF_ALL (OFF_CNT + 20)            // 1 uint global pair-done counter
#define OFF_PL  (OFF_ALL + 1)             // 20 float pair losses

__device__ __forceinline__ int gidx(int n, int c, int h, int w, int d) {
  return (((n * C_ + c) * HWD + h) * HWD + w) * HWD + d;
}

// ---- kernel 1: gather x,y neighborhoods -> compact ws; fold y channel-mean -
// 960 blocks x 64 thr; block = (which, s, c). Reads HBM scattered ONCE.
__global__ void k_gather(const float* __restrict__ x, const float* __restrict__ y,
                         const int* __restrict__ hi, const int* __restrict__ wi,
                         const int* __restrict__ di, float* __restrict__ ws) {
  int b = blockIdx.x, t = threadIdx.x;
  if (b < 160) ws[OFF_CM + b * 64 + t] = 0.f;        // zero colmax (10240)
  if (b == 160 && t < 41) ws[OFF_CNT + t] = 0.f;     // zero counters + losses
  int which = b >= 480;                              // 0 = y, 1 = x
  int r = which ? b - 480 : b;
  int s = r / C_, c = r % C_;
  const float* src = which ? x : y;
  int h0 = hi[s] - PADK, w0 = wi[s] - PADK, d0 = di[s] - PADK;
  float* dst = ws + (which ? OFF_GX : OFF_GY) + (s * 96 + 2 * c) * 512;
  float sum = 0.f;
#pragma unroll
  for (int j = 0; j < 16; ++j) {
    int n = j >> 3, m = ((j & 7) << 6) + t;          // coalesced compact store
    float v = src[gidx(n, c, h0 + (m >> 6), w0 + ((m >> 3) & 7), d0 + (m & 7))];
    dst[n * 512 + m] = v;
    sum += v;
  }
  if (!which) {
#pragma unroll
    for (int off = 32; off; off >>= 1) sum += __shfl_xor(sum, off);
    if (t == 0) ws[OFF_MU + s * C_ + c] = sum * (1.0f / 1024.0f);
  }
}

// ---- kernel 2: center + L2-normalize IN PLACE on the compact buffer -------
// 320 blocks x 256 thr; 4 lanes per column (12 channels each). L2/L3-resident.
__global__ void k_norm2(float* __restrict__ ws) {
  int g = blockIdx.x * 256 + threadIdx.x;   // 0..81919
  int col = g >> 2;                         // 0..20479
  int q = threadIdx.x & 3;                  // channel quarter
  int which = col >= 10240;                 // 0 = y, 1 = x
  int cix = which ? col - 10240 : col;
  int pair = cix >> 9, m = cix & 511;
  int s = pair >> 1, n = pair & 1;
  float* base = ws + (which ? OFF_GX : OFF_GY) + (s * 96 + n) * 512 + m;
  const float* mus = ws + OFF_MU + s * C_;
  int c0 = q * 12;
  float v[12];
  float ss = 0.f;
#pragma unroll
  for (int j = 0; j < 12; ++j) {
    v[j] = base[(c0 + j) * 1024] - mus[c0 + j];
    ss += v[j] * v[j];
  }
  // combine the 4 quarters of this column (aligned 4-lane group)
  ss += __shfl_xor(ss, 1);
  ss += __shfl_xor(ss, 2);
  float sc = 1.0f / fmaxf(sqrtf(ss), 1e-12f);
#pragma unroll
  for (int j = 0; j < 12; ++j) base[(c0 + j) * 1024] = v[j] * sc;
}

// ---- kernel 3: dist + row-softmax + column-max + fused final --------------
// 320 blocks x 256 thr; block = (pair, tile of 32 rows); 8 rows/wave.
__global__ __launch_bounds__(256, 4) void k_main(float* __restrict__ ws,
                                                 float* __restrict__ out) {
  int b = blockIdx.x;
  int pair = b >> 4, tile = b & 15;
  int s = pair >> 1, n = pair & 1;
  int t = threadIdx.x, lane = t & 63, wv = t >> 6;

  __shared__ float xl[C_ * 32];        // x tile: [c][row] (32 rows)
  __shared__ float yl[12 * YPITCH];    // y chunk: [c_rel][p]

  const float* xsrc = ws + OFF_GX + (s * 96 + n) * 512 + tile * 32;
#pragma unroll
  for (int i = 0; i < 2; ++i) {
    int li = t + 256 * i;              // 384 float4s
    if (li < 384) {
      int c = li >> 3, r4 = (li & 7) << 2;
      *(float4*)(xl + c * 32 + r4) = *(const float4*)(xsrc + c * 1024 + r4);
    }
  }

  float acc[8][8];
#pragma unroll
  for (int r = 0; r < 8; ++r)
#pragma unroll
    for (int k = 0; k < 8; ++k) acc[r][k] = 0.f;

  const float* ysrc = ws + OFF_GY + (s * 96 + n) * 512;
  for (int chunk = 0; chunk < 4; ++chunk) {
    __syncthreads();
#pragma unroll
    for (int i = 0; i < 6; ++i) {      // 12 channels x 512 = 1536 float4s
      int li = t + 256 * i;
      int cr = li >> 7, p4 = (li & 127) << 2;
      *(float4*)(yl + cr * YPITCH + p4) =
          *(const float4*)(ysrc + (chunk * 12 + cr) * 1024 + p4);
    }
    __syncthreads();
#pragma unroll
    for (int cr = 0; cr < 12; ++cr) {
      float yv[8];
#pragma unroll
      for (int k = 0; k < 8; ++k) yv[k] = yl[cr * YPITCH + lane + 64 * k];
      int c = chunk * 12 + cr;
#pragma unroll
      for (int r4 = 0; r4 < 2; ++r4) {
        float4 xv = *(const float4*)(xl + c * 32 + wv * 8 + r4 * 4); // broadcast
#pragma unroll
        for (int k = 0; k < 8; ++k) {
          acc[r4 * 4 + 0][k] += xv.x * yv[k];
          acc[r4 * 4 + 1][k] += xv.y * yv[k];
          acc[r4 * 4 + 2][k] += xv.z * yv[k];
          acc[r4 * 4 + 3][k] += xv.w * yv[k];
        }
      }
    }
  }

  // epilogue: per row min -> softmax over p -> column-max accumulate
  float cmax[8];
#pragma unroll
  for (int k = 0; k < 8; ++k) cmax[k] = 0.f;
#pragma unroll
  for (int r = 0; r < 8; ++r) {
    float dmin = 3.4e38f;
#pragma unroll
    for (int k = 0; k < 8; ++k) {
      float d = 1.0f - acc[r][k];
      acc[r][k] = d;
      dmin = fminf(dmin, d);
    }
#pragma unroll
    for (int off = 32; off; off >>= 1) dmin = fminf(dmin, __shfl_xor(dmin, off));
    float inv = 2.0f / (dmin + 1e-5f);  // logits <= 2, no overflow
    float e[8], sm = 0.f;
#pragma unroll
    for (int k = 0; k < 8; ++k) {
      e[k] = __expf(2.0f - acc[r][k] * inv);
      sm += e[k];
    }
#pragma unroll
    for (int off = 32; off; off >>= 1) sm += __shfl_xor(sm, off);
    float rs = 1.0f / sm;
#pragma unroll
    for (int k = 0; k < 8; ++k) cmax[k] = fmaxf(cmax[k], e[k] * rs);
  }
  unsigned* cmu = (unsigned*)(ws + OFF_CM) + pair * M_;
#pragma unroll
  for (int k = 0; k < 8; ++k)
    atomicMax(&cmu[lane + 64 * k], __float_as_uint(cmax[k]));

  // ---- fused final: last block per pair reduces; last pair writes out ----
  __threadfence();
  __shared__ unsigned arr;
  if (t == 0) arr = atomicAdd((unsigned*)(ws + OFF_CNT) + pair, 1u);
  __syncthreads();
  if (arr == 15) {
    float sum = __uint_as_float(atomicOr(&cmu[t], 0u)) +
                __uint_as_float(atomicOr(&cmu[t + 256], 0u));
#pragma unroll
    for (int off = 32; off; off >>= 1) sum += __shfl_xor(sum, off);
    __shared__ float red[4];
    if (lane == 0) red[wv] = sum;
    __syncthreads();
    if (t == 0) {
      float tot = red[0] + red[1] + red[2] + red[3];
      float loss = -logf(tot * (1.0f / 512.0f) + 1e-5f);
      atomicExch((unsigned*)(ws + OFF_PL) + pair, __float_as_uint(loss));
      __threadfence();
      unsigned d = atomicAdd((unsigned*)(ws + OFF_ALL), 1u);
      if (d == PAIRS - 1) {
        float tt = 0.f;
        for (int i = 0; i < PAIRS; ++i)
          tt += __uint_as_float(atomicOr((unsigned*)(ws + OFF_PL) + i, 0u));
        out[0] = tt * (1.0f / (float)PAIRS);
      }
    }
  }
}

extern "C" void kernel_launch(void* const* d_in, const int* in_sizes, int n_in,
                              void* d_out, int out_size, void* d_ws, size_t ws_size,
                              hipStream_t stream) {
  const float* x = (const float*)d_in[0];
  const float* y = (const float*)d_in[1];
  const int* hi = (const int*)d_in[2];
  const int* wi = (const int*)d_in[3];
  const int* di = (const int*)d_in[4];
  float* ws = (float*)d_ws;
  float* out = (float*)d_out;

  k_gather<<<960, 64, 0, stream>>>(x, y, hi, wi, di, ws);
  k_norm2<<<320, 256, 0, stream>>>(ws);
  k_main<<<PAIRS * 16, 256, 0, stream>>>(ws, out);
}